// Round 2
// baseline (817.485 us; speedup 1.0000x reference)
//
#include <hip/hip_runtime.h>

#define B_N   262144
#define IN_N  64
#define H_N   64
#define NT    8
#define TILE_M 64
#define GATE_ROWS 256   // 4*H

// ---------------- helpers ----------------

__device__ __forceinline__ int last_type(const int* __restrict__ at, int b) {
    const int4* p = (const int4*)(at + (size_t)b * 8);
    int4 a0 = p[0], a1 = p[1];
    int t = -1;
    if (a0.x > 0) t = 0;
    if (a0.y > 0) t = 1;
    if (a0.z > 0) t = 2;
    if (a0.w > 0) t = 3;
    if (a1.x > 0) t = 4;
    if (a1.y > 0) t = 5;
    if (a1.z > 0) t = 6;
    if (a1.w > 0) t = 7;
    return t;
}

__device__ __forceinline__ float sigmoidf_(float x) {
    return 1.0f / (1.0f + __expf(-x));
}
__device__ __forceinline__ float tanhf_(float x) {
    float xc = fminf(fmaxf(x, -20.0f), 20.0f);
    float e  = __expf(2.0f * xc);
    return (e - 1.0f) / (e + 1.0f);
}

// ws layout (ints): [0..15] cnt, [16..31] off, [32..47] toff, [48..63] cur, [64..) perm[B]

// ---------------- kernel 1a: histogram ----------------
__global__ void k_hist(const int* __restrict__ at, int* __restrict__ cnt) {
    __shared__ int h[NT];
    int tid = threadIdx.x;
    if (tid < NT) h[tid] = 0;
    __syncthreads();
    int b = blockIdx.x * blockDim.x + tid;
    int t = last_type(at, b);
    if (t >= 0) atomicAdd(&h[t], 1);
    __syncthreads();
    if (tid < NT && h[tid] > 0) atomicAdd(&cnt[tid], h[tid]);
}

// ---------------- kernel 1b: scan (1 thread) ----------------
__global__ void k_scan(int* __restrict__ ws) {
    int* cnt  = ws;
    int* off  = ws + 16;
    int* toff = ws + 32;
    int* cur  = ws + 48;
    int o = 0, to = 0;
    for (int t = 0; t < NT; ++t) {
        off[t] = o; cur[t] = o; toff[t] = to;
        o  += cnt[t];
        to += (cnt[t] + TILE_M - 1) / TILE_M;
    }
    off[NT] = o; toff[NT] = to;
}

// ---------------- kernel 1c: scatter perm + zero typeless ----------------
__global__ void k_scatter(const int* __restrict__ at, int* __restrict__ cur,
                          int* __restrict__ perm,
                          float* __restrict__ outy, float* __restrict__ outh,
                          float* __restrict__ outc) {
    __shared__ int lcnt[NT];
    __shared__ int lbase[NT];
    int tid = threadIdx.x;
    if (tid < NT) lcnt[tid] = 0;
    __syncthreads();
    int b = blockIdx.x * blockDim.x + tid;
    int t = last_type(at, b);
    int lrank = 0;
    if (t >= 0) lrank = atomicAdd(&lcnt[t], 1);
    __syncthreads();
    if (tid < NT) lbase[tid] = (lcnt[tid] > 0) ? atomicAdd(&cur[tid], lcnt[tid]) : 0;
    __syncthreads();
    if (t >= 0) {
        perm[lbase[t] + lrank] = b;
    } else {
        float4 z = {0.f, 0.f, 0.f, 0.f};
        float4* py = (float4*)(outy + (size_t)b * H_N);
        float4* ph = (float4*)(outh + (size_t)b * H_N);
        float4* pc = (float4*)(outc + (size_t)b * H_N);
        #pragma unroll
        for (int i = 0; i < 16; ++i) { py[i] = z; ph[i] = z; pc[i] = z; }
    }
}

// ---------------- kernel 2: per-type batched GEMV + LSTM epilogue ----------------
__global__ void k_gemm(const float* __restrict__ x, const float* __restrict__ h0,
                       const float* __restrict__ c0,
                       const float* __restrict__ Wih, const float* __restrict__ Whh,
                       const float* __restrict__ bih, const float* __restrict__ bhh,
                       const int* __restrict__ ws, const int* __restrict__ perm,
                       float* __restrict__ outy, float* __restrict__ outh,
                       float* __restrict__ outc) {
    const int* cnt  = ws;
    const int* off  = ws + 16;
    const int* toff = ws + 32;

    int bid = blockIdx.x;
    int ntiles = toff[NT];
    if (bid >= ntiles) return;

    // find bucket type: smallest t with bid < toff[t+1]
    int t = 0;
    #pragma unroll
    for (int tt = 0; tt < NT - 1; ++tt) {
        if (bid >= toff[tt + 1]) t = tt + 1;
    }
    int ltile  = bid - toff[t];
    int mbase  = off[t] + ltile * TILE_M;
    int mcount = min(TILE_M, cnt[t] - ltile * TILE_M);

    __shared__ float xh[128][68];     // [k][m], stride 68 keeps float4 16B-aligned
    __shared__ int   s_perm[TILE_M];

    int tid = threadIdx.x;
    if (tid < TILE_M) s_perm[tid] = (tid < mcount) ? perm[mbase + tid] : -1;
    __syncthreads();

    // gather x and h rows into LDS: 16 lanes per element row, float4 each
    {
        int p    = tid & 15;     // which float4 within the 64-float row
        int mloc = tid >> 4;     // 0..15
        #pragma unroll
        for (int pass = 0; pass < 4; ++pass) {
            int m = mloc + pass * 16;
            int e = s_perm[m];
            float4 vx = {0.f,0.f,0.f,0.f}, vh = {0.f,0.f,0.f,0.f};
            if (e >= 0) {
                vx = ((const float4*)(x  + (size_t)e * IN_N))[p];
                vh = ((const float4*)(h0 + (size_t)e * H_N))[p];
            }
            int k0 = p * 4;
            xh[k0 + 0][m] = vx.x; xh[k0 + 1][m] = vx.y;
            xh[k0 + 2][m] = vx.z; xh[k0 + 3][m] = vx.w;
            xh[64 + k0 + 0][m] = vh.x; xh[64 + k0 + 1][m] = vh.y;
            xh[64 + k0 + 2][m] = vh.z; xh[64 + k0 + 3][m] = vh.w;
        }
    }
    __syncthreads();

    int j0   = tid & 63;   // row within each gate; wave = consecutive j0 -> coalesced epilogue
    int mgrp = tid >> 6;   // 0..3
    int m0   = mgrp * 16;

    float acc[4][16];
    #pragma unroll
    for (int g = 0; g < 4; ++g)
        #pragma unroll
        for (int i = 0; i < 16; ++i) acc[g][i] = 0.f;

    // stream weights (registers) x LDS-broadcast activations
    #pragma unroll
    for (int half = 0; half < 2; ++half) {
        const float* W = (half == 0) ? (Wih + (size_t)t * GATE_ROWS * 64)
                                     : (Whh + (size_t)t * GATE_ROWS * 64);
        int kbase = half * 64;
        for (int kc = 0; kc < 16; ++kc) {
            float4 w0 = *(const float4*)(W + (size_t)(  0 + j0) * 64 + kc * 4);
            float4 w1 = *(const float4*)(W + (size_t)( 64 + j0) * 64 + kc * 4);
            float4 w2 = *(const float4*)(W + (size_t)(128 + j0) * 64 + kc * 4);
            float4 w3 = *(const float4*)(W + (size_t)(192 + j0) * 64 + kc * 4);
            #pragma unroll
            for (int kk = 0; kk < 4; ++kk) {
                int k = kbase + kc * 4 + kk;
                float4 xv0 = *(const float4*)&xh[k][m0 + 0];
                float4 xv1 = *(const float4*)&xh[k][m0 + 4];
                float4 xv2 = *(const float4*)&xh[k][m0 + 8];
                float4 xv3 = *(const float4*)&xh[k][m0 + 12];
                float wg0, wg1, wg2, wg3;
                if      (kk == 0) { wg0 = w0.x; wg1 = w1.x; wg2 = w2.x; wg3 = w3.x; }
                else if (kk == 1) { wg0 = w0.y; wg1 = w1.y; wg2 = w2.y; wg3 = w3.y; }
                else if (kk == 2) { wg0 = w0.z; wg1 = w1.z; wg2 = w2.z; wg3 = w3.z; }
                else              { wg0 = w0.w; wg1 = w1.w; wg2 = w2.w; wg3 = w3.w; }
                #pragma unroll
                for (int q = 0; q < 4; ++q) {
                    float4 xv = (q == 0) ? xv0 : (q == 1) ? xv1 : (q == 2) ? xv2 : xv3;
                    acc[0][q*4+0] += wg0 * xv.x; acc[0][q*4+1] += wg0 * xv.y;
                    acc[0][q*4+2] += wg0 * xv.z; acc[0][q*4+3] += wg0 * xv.w;
                    acc[1][q*4+0] += wg1 * xv.x; acc[1][q*4+1] += wg1 * xv.y;
                    acc[1][q*4+2] += wg1 * xv.z; acc[1][q*4+3] += wg1 * xv.w;
                    acc[2][q*4+0] += wg2 * xv.x; acc[2][q*4+1] += wg2 * xv.y;
                    acc[2][q*4+2] += wg2 * xv.z; acc[2][q*4+3] += wg2 * xv.w;
                    acc[3][q*4+0] += wg3 * xv.x; acc[3][q*4+1] += wg3 * xv.y;
                    acc[3][q*4+2] += wg3 * xv.z; acc[3][q*4+3] += wg3 * xv.w;
                }
            }
        }
    }

    // biases (same for every m)
    float bi = bih[t * GATE_ROWS +   0 + j0] + bhh[t * GATE_ROWS +   0 + j0];
    float bf = bih[t * GATE_ROWS +  64 + j0] + bhh[t * GATE_ROWS +  64 + j0];
    float bg = bih[t * GATE_ROWS + 128 + j0] + bhh[t * GATE_ROWS + 128 + j0];
    float bo = bih[t * GATE_ROWS + 192 + j0] + bhh[t * GATE_ROWS + 192 + j0];

    // epilogue: per element, fully coalesced (wave = 64 consecutive j0, uniform e)
    #pragma unroll
    for (int i = 0; i < 16; ++i) {
        int m = m0 + i;
        if (m >= mcount) break;
        int e = s_perm[m];
        float ig = sigmoidf_(acc[0][i] + bi);
        float fg = sigmoidf_(acc[1][i] + bf);
        float gg = tanhf_(acc[2][i] + bg);
        float og = sigmoidf_(acc[3][i] + bo);
        float cv = c0[(size_t)e * H_N + j0];
        float ct = fg * cv + ig * gg;
        float ht = og * tanhf_(ct);
        size_t o = (size_t)e * H_N + j0;
        outy[o] = ht;
        outh[o] = ht;
        outc[o] = ct;
    }
}

// ---------------- launch ----------------
extern "C" void kernel_launch(void* const* d_in, const int* in_sizes, int n_in,
                              void* d_out, int out_size, void* d_ws, size_t ws_size,
                              hipStream_t stream) {
    const float* x   = (const float*)d_in[0];
    const float* h0  = (const float*)d_in[1];
    const float* c0  = (const float*)d_in[2];
    const int*   at  = (const int*)d_in[3];
    const float* Wih = (const float*)d_in[4];
    const float* Whh = (const float*)d_in[5];
    const float* bih = (const float*)d_in[6];
    const float* bhh = (const float*)d_in[7];

    float* outy = (float*)d_out;
    float* outh = outy + (size_t)B_N * H_N;
    float* outc = outh + (size_t)B_N * H_N;

    int* ws   = (int*)d_ws;
    int* cnt  = ws;
    int* cur  = ws + 48;
    int* perm = ws + 64;

    hipMemsetAsync(cnt, 0, 16 * sizeof(int), stream);
    k_hist<<<B_N / 256, 256, 0, stream>>>(at, cnt);
    k_scan<<<1, 1, 0, stream>>>(ws);
    k_scatter<<<B_N / 256, 256, 0, stream>>>(at, cur, perm, outy, outh, outc);
    k_gemm<<<B_N / TILE_M + NT, 256, 0, stream>>>(x, h0, c0, Wih, Whh, bih, bhh,
                                                  ws, perm, outy, outh, outc);
}

// Round 9
// 449.487 us; speedup vs baseline: 1.8187x; 1.8187x over previous
//
#include <hip/hip_runtime.h>

#define B_N    262144
#define NT     8
#define TILE_M 64
#define GATE_ROWS 256

typedef __attribute__((ext_vector_type(8))) short short8;
typedef __attribute__((ext_vector_type(4))) float f32x4;

// ---------------- helpers ----------------

__device__ __forceinline__ unsigned short f2bf(float f) {   // RNE f32->bf16
    unsigned int u = __float_as_uint(f);
    u += 0x7fffu + ((u >> 16) & 1u);
    return (unsigned short)(u >> 16);
}
__device__ __forceinline__ float bf2f(unsigned short h) {
    return __uint_as_float(((unsigned int)h) << 16);
}

__device__ __forceinline__ int last_type(const int* __restrict__ at, int b) {
    const int4* p = (const int4*)(at + (size_t)b * 8);
    int4 a0 = p[0], a1 = p[1];
    int t = -1;
    if (a0.x > 0) t = 0;
    if (a0.y > 0) t = 1;
    if (a0.z > 0) t = 2;
    if (a0.w > 0) t = 3;
    if (a1.x > 0) t = 4;
    if (a1.y > 0) t = 5;
    if (a1.z > 0) t = 6;
    if (a1.w > 0) t = 7;
    return t;
}

__device__ __forceinline__ float sigmoidf_(float x) {
    return 1.0f / (1.0f + __expf(-x));
}
__device__ __forceinline__ float tanhf_(float x) {
    float xc = fminf(fmaxf(x, -20.0f), 20.0f);
    float e  = __expf(2.0f * xc);
    return (e - 1.0f) / (e + 1.0f);
}

// ws layout (ints): [0..15] cnt, [16..31] cur (zeroed), [64..64+B_N) perm
// Path A additionally: whi (2048x128 bf16), wlo (2048x128 bf16) after perm.

// ---------------- kernel 0 (Path A): weight pre-split ----------------
__global__ void k_wprep(const float* __restrict__ Wih, const float* __restrict__ Whh,
                        unsigned short* __restrict__ whi, unsigned short* __restrict__ wlo) {
    int idx = blockIdx.x * 256 + threadIdx.x;   // [0, NT*256*128)
    int rg  = idx >> 7;
    int k   = idx & 127;
    int t   = rg >> 8;
    int row = rg & 255;
    float f = (k < 64) ? Wih[(size_t)t * 16384 + row * 64 + k]
                       : Whh[(size_t)t * 16384 + row * 64 + (k - 64)];
    unsigned short hi = f2bf(f);
    unsigned short lo = f2bf(f - bf2f(hi));
    whi[idx] = hi;
    wlo[idx] = lo;
}

// ---------------- kernel 1: histogram ----------------
__global__ void k_hist(const int* __restrict__ at, int* __restrict__ cnt) {
    __shared__ int h[NT];
    int tid = threadIdx.x;
    if (tid < NT) h[tid] = 0;
    __syncthreads();
    int b = blockIdx.x * blockDim.x + tid;
    int t = last_type(at, b);
    if (t >= 0) atomicAdd(&h[t], 1);
    __syncthreads();
    if (tid < NT && h[tid] > 0) atomicAdd(&cnt[tid], h[tid]);
}

// ---------------- kernel 2: scatter perm + zero typeless ----------------
__global__ void k_scatter(const int* __restrict__ at, int* __restrict__ ws,
                          int* __restrict__ perm,
                          float* __restrict__ outy, float* __restrict__ outh,
                          float* __restrict__ outc) {
    const int* cnt = ws;
    int*       cur = ws + 16;
    __shared__ int lcnt[NT];
    __shared__ int lbase[NT];
    int tid = threadIdx.x;
    if (tid < NT) lcnt[tid] = 0;
    __syncthreads();
    int b = blockIdx.x * blockDim.x + tid;
    int t = last_type(at, b);
    int lrank = 0;
    if (t >= 0) lrank = atomicAdd(&lcnt[t], 1);
    __syncthreads();
    if (tid < NT) {
        int off = 0;
        #pragma unroll
        for (int u = 0; u < NT; ++u) if (u < tid) off += cnt[u];
        lbase[tid] = (lcnt[tid] > 0) ? (off + atomicAdd(&cur[tid], lcnt[tid])) : 0;
    }
    __syncthreads();
    if (t >= 0) {
        perm[lbase[t] + lrank] = b;
    } else {
        float4 z = {0.f, 0.f, 0.f, 0.f};
        float4* py = (float4*)(outy + (size_t)b * 64);
        float4* ph = (float4*)(outh + (size_t)b * 64);
        float4* pc = (float4*)(outc + (size_t)b * 64);
        #pragma unroll
        for (int i = 0; i < 16; ++i) { py[i] = z; ph[i] = z; pc[i] = z; }
    }
}

// ---------------- kernel 3A: bf16x3 MFMA batched GEMM + LSTM epilogue ----------------
__global__ __launch_bounds__(256, 3)
void k_mfma(const float* __restrict__ x, const float* __restrict__ h0,
            const float* __restrict__ c0,
            const unsigned short* __restrict__ whi_g,
            const unsigned short* __restrict__ wlo_g,
            const float* __restrict__ bih, const float* __restrict__ bhh,
            const int* __restrict__ ws, const int* __restrict__ perm,
            float* __restrict__ outy, float* __restrict__ outh,
            float* __restrict__ outc) {
    const int* cnt = ws;

    int off_[NT + 1], toff_[NT + 1];
    {
        int o = 0, to = 0;
        #pragma unroll
        for (int u = 0; u < NT; ++u) {
            off_[u] = o; toff_[u] = to;
            int c = cnt[u];
            o += c; to += (c + TILE_M - 1) / TILE_M;
        }
        off_[NT] = o; toff_[NT] = to;
    }

    int bid = blockIdx.x;
    if (bid >= toff_[NT]) return;

    int t = 0;
    #pragma unroll
    for (int tt = 0; tt < NT - 1; ++tt)
        if (bid >= toff_[tt + 1]) t = tt + 1;
    int ltile  = bid - toff_[t];
    int mbase  = off_[t] + ltile * TILE_M;
    int mcount = min(TILE_M, cnt[t] - ltile * TILE_M);

    __shared__ unsigned short lds_hi[64][136];   // aliased to lds_h after MFMA
    __shared__ unsigned short lds_lo[64][136];   // aliased to lds_c after MFMA
    __shared__ float          lds_c0[64][68];
    __shared__ int            s_perm[TILE_M];

    int tid = threadIdx.x;
    if (tid < TILE_M) s_perm[tid] = (tid < mcount) ? perm[mbase + tid] : -1;
    __syncthreads();

    {
        int p    = tid & 15;
        int mloc = tid >> 4;
        #pragma unroll
        for (int pass = 0; pass < 4; ++pass) {
            int m = mloc + pass * 16;
            int e = s_perm[m];
            float4 vx = {0.f,0.f,0.f,0.f}, vh = {0.f,0.f,0.f,0.f}, vc = {0.f,0.f,0.f,0.f};
            if (e >= 0) {
                vx = ((const float4*)(x  + (size_t)e * 64))[p];
                vh = ((const float4*)(h0 + (size_t)e * 64))[p];
                vc = ((const float4*)(c0 + (size_t)e * 64))[p];
            }
            unsigned short hx0 = f2bf(vx.x), hx1 = f2bf(vx.y), hx2 = f2bf(vx.z), hx3 = f2bf(vx.w);
            unsigned short hh0 = f2bf(vh.x), hh1 = f2bf(vh.y), hh2 = f2bf(vh.z), hh3 = f2bf(vh.w);
            ushort4 HX = {hx0, hx1, hx2, hx3};
            ushort4 LX = {f2bf(vx.x - bf2f(hx0)), f2bf(vx.y - bf2f(hx1)),
                          f2bf(vx.z - bf2f(hx2)), f2bf(vx.w - bf2f(hx3))};
            ushort4 HH = {hh0, hh1, hh2, hh3};
            ushort4 LH = {f2bf(vh.x - bf2f(hh0)), f2bf(vh.y - bf2f(hh1)),
                          f2bf(vh.z - bf2f(hh2)), f2bf(vh.w - bf2f(hh3))};
            *(ushort4*)&lds_hi[m][p * 4]      = HX;
            *(ushort4*)&lds_lo[m][p * 4]      = LX;
            *(ushort4*)&lds_hi[m][64 + p * 4] = HH;
            *(ushort4*)&lds_lo[m][64 + p * 4] = LH;
            *(float4*)&lds_c0[m][p * 4]       = vc;
        }
    }
    __syncthreads();

    int w  = tid >> 6;
    int l  = tid & 63;
    int lr = l & 15;
    int lk = l >> 4;

    f32x4 acc[4][4];
    #pragma unroll
    for (int g = 0; g < 4; ++g)
        #pragma unroll
        for (int ct = 0; ct < 4; ++ct)
            acc[g][ct] = (f32x4){0.f, 0.f, 0.f, 0.f};

    const unsigned short* Whi = whi_g + (size_t)t * 32768;
    const unsigned short* Wlo = wlo_g + (size_t)t * 32768;

    #pragma unroll
    for (int ks = 0; ks < 4; ++ks) {
        int k0 = ks * 32 + lk * 8;
        short8 ahi[4], alo[4];
        #pragma unroll
        for (int g = 0; g < 4; ++g) {
            int row = g * 64 + w * 16 + lr;
            ahi[g] = *(const short8*)(Whi + (size_t)row * 128 + k0);
            alo[g] = *(const short8*)(Wlo + (size_t)row * 128 + k0);
        }
        #pragma unroll
        for (int ct = 0; ct < 4; ++ct) {
            int m = ct * 16 + lr;
            short8 bhi = *(const short8*)&lds_hi[m][k0];
            short8 blo = *(const short8*)&lds_lo[m][k0];
            #pragma unroll
            for (int g = 0; g < 4; ++g) {
                acc[g][ct] = __builtin_amdgcn_mfma_f32_16x16x32_bf16(ahi[g], bhi, acc[g][ct], 0, 0, 0);
                acc[g][ct] = __builtin_amdgcn_mfma_f32_16x16x32_bf16(ahi[g], blo, acc[g][ct], 0, 0, 0);
                acc[g][ct] = __builtin_amdgcn_mfma_f32_16x16x32_bf16(alo[g], bhi, acc[g][ct], 0, 0, 0);
            }
        }
    }
    __syncthreads();

    float bias[4][4];
    #pragma unroll
    for (int r = 0; r < 4; ++r) {
        int j = w * 16 + lk * 4 + r;
        #pragma unroll
        for (int g = 0; g < 4; ++g)
            bias[g][r] = bih[t * 256 + g * 64 + j] + bhh[t * 256 + g * 64 + j];
    }

    float (*lds_h)[68] = (float(*)[68]) & lds_hi[0][0];
    float (*lds_c)[68] = (float(*)[68]) & lds_lo[0][0];

    #pragma unroll
    for (int ct = 0; ct < 4; ++ct) {
        int m = ct * 16 + lr;
        #pragma unroll
        for (int r = 0; r < 4; ++r) {
            int j  = w * 16 + lk * 4 + r;
            float ig = sigmoidf_(acc[0][ct][r] + bias[0][r]);
            float fg = sigmoidf_(acc[1][ct][r] + bias[1][r]);
            float gg = tanhf_  (acc[2][ct][r] + bias[2][r]);
            float og = sigmoidf_(acc[3][ct][r] + bias[3][r]);
            float cv  = lds_c0[m][j];
            float ctv = fg * cv + ig * gg;
            float htv = og * tanhf_(ctv);
            lds_h[m][j] = htv;
            lds_c[m][j] = ctv;
        }
    }
    __syncthreads();

    {
        int p  = tid & 15;
        int mq = tid >> 4;
        #pragma unroll
        for (int rep = 0; rep < 4; ++rep) {
            int m = mq + rep * 16;
            int e = s_perm[m];
            if (e >= 0) {
                float4 vh4 = *(float4*)&lds_h[m][p * 4];
                float4 vc4 = *(float4*)&lds_c[m][p * 4];
                ((float4*)(outy + (size_t)e * 64))[p] = vh4;
                ((float4*)(outh + (size_t)e * 64))[p] = vh4;
                ((float4*)(outc + (size_t)e * 64))[p] = vc4;
            }
        }
    }
}

// ---------------- kernel 3B (fallback): fp32 two-pass GEMV + epilogue ----------------
__global__ __launch_bounds__(256, 4)
void k_gemm(const float* __restrict__ x, const float* __restrict__ h0,
            const float* __restrict__ c0,
            const float* __restrict__ Wih, const float* __restrict__ Whh,
            const float* __restrict__ bih, const float* __restrict__ bhh,
            const int* __restrict__ ws, const int* __restrict__ perm,
            float* __restrict__ outy, float* __restrict__ outh,
            float* __restrict__ outc) {
    const int* cnt = ws;

    int off_[NT + 1], toff_[NT + 1];
    {
        int o = 0, to = 0;
        #pragma unroll
        for (int u = 0; u < NT; ++u) {
            off_[u] = o; toff_[u] = to;
            int c = cnt[u];
            o += c; to += (c + TILE_M - 1) / TILE_M;
        }
        off_[NT] = o; toff_[NT] = to;
    }

    int bid = blockIdx.x;
    if (bid >= toff_[NT]) return;

    int t = 0;
    #pragma unroll
    for (int tt = 0; tt < NT - 1; ++tt)
        if (bid >= toff_[tt + 1]) t = tt + 1;
    int ltile  = bid - toff_[t];
    int mbase  = off_[t] + ltile * TILE_M;
    int mcount = min(TILE_M, cnt[t] - ltile * TILE_M);

    __shared__ float xh[128][68];
    __shared__ int   s_perm[TILE_M];

    int tid = threadIdx.x;
    if (tid < TILE_M) s_perm[tid] = (tid < mcount) ? perm[mbase + tid] : -1;
    __syncthreads();

    {
        int p    = tid & 15;
        int mloc = tid >> 4;
        #pragma unroll
        for (int pass = 0; pass < 4; ++pass) {
            int m = mloc + pass * 16;
            int e = s_perm[m];
            float4 vx = {0.f,0.f,0.f,0.f}, vh = {0.f,0.f,0.f,0.f};
            if (e >= 0) {
                vx = ((const float4*)(x  + (size_t)e * 64))[p];
                vh = ((const float4*)(h0 + (size_t)e * 64))[p];
            }
            int k0 = p * 4;
            xh[k0 + 0][m] = vx.x; xh[k0 + 1][m] = vx.y;
            xh[k0 + 2][m] = vx.z; xh[k0 + 3][m] = vx.w;
            xh[64 + k0 + 0][m] = vh.x; xh[64 + k0 + 1][m] = vh.y;
            xh[64 + k0 + 2][m] = vh.z; xh[64 + k0 + 3][m] = vh.w;
        }
    }
    __syncthreads();

    int j0   = tid & 63;
    int mgrp = tid >> 6;
    int m0   = mgrp * 16;

    const size_t wbase = (size_t)t * GATE_ROWS * 64;

    float pg[16];
    {
        float a0[16], a1[16];
        #pragma unroll
        for (int i = 0; i < 16; ++i) { a0[i] = 0.f; a1[i] = 0.f; }
        #pragma unroll
        for (int half = 0; half < 2; ++half) {
            const float* W = (half == 0) ? (Wih + wbase) : (Whh + wbase);
            int kbase = half * 64;
            for (int kc = 0; kc < 16; ++kc) {
                float4 wA = *(const float4*)(W + (size_t)(  0 + j0) * 64 + kc * 4);
                float4 wB = *(const float4*)(W + (size_t)(128 + j0) * 64 + kc * 4);
                #pragma unroll
                for (int kk = 0; kk < 4; ++kk) {
                    int k = kbase + kc * 4 + kk;
                    float4 xv0 = *(const float4*)&xh[k][m0 + 0];
                    float4 xv1 = *(const float4*)&xh[k][m0 + 4];
                    float4 xv2 = *(const float4*)&xh[k][m0 + 8];
                    float4 xv3 = *(const float4*)&xh[k][m0 + 12];
                    float wa = (kk == 0) ? wA.x : (kk == 1) ? wA.y : (kk == 2) ? wA.z : wA.w;
                    float wb = (kk == 0) ? wB.x : (kk == 1) ? wB.y : (kk == 2) ? wB.z : wB.w;
                    #pragma unroll
                    for (int q = 0; q < 4; ++q) {
                        float4 xv = (q == 0) ? xv0 : (q == 1) ? xv1 : (q == 2) ? xv2 : xv3;
                        a0[q*4+0] += wa * xv.x; a0[q*4+1] += wa * xv.y;
                        a0[q*4+2] += wa * xv.z; a0[q*4+3] += wa * xv.w;
                        a1[q*4+0] += wb * xv.x; a1[q*4+1] += wb * xv.y;
                        a1[q*4+2] += wb * xv.z; a1[q*4+3] += wb * xv.w;
                    }
                }
            }
        }
        float bi = bih[t * GATE_ROWS +   0 + j0] + bhh[t * GATE_ROWS +   0 + j0];
        float bg = bih[t * GATE_ROWS + 128 + j0] + bhh[t * GATE_ROWS + 128 + j0];
        #pragma unroll
        for (int i = 0; i < 16; ++i)
            pg[i] = sigmoidf_(a0[i] + bi) * tanhf_(a1[i] + bg);
    }

    {
        float a0[16], a1[16];
        #pragma unroll
        for (int i = 0; i < 16; ++i) { a0[i] = 0.f; a1[i] = 0.f; }
        #pragma unroll
        for (int half = 0; half < 2; ++half) {
            const float* W = (half == 0) ? (Wih + wbase) : (Whh + wbase);
            int kbase = half * 64;
            for (int kc = 0; kc < 16; ++kc) {
                float4 wA = *(const float4*)(W + (size_t)( 64 + j0) * 64 + kc * 4);
                float4 wB = *(const float4*)(W + (size_t)(192 + j0) * 64 + kc * 4);
                #pragma unroll
                for (int kk = 0; kk < 4; ++kk) {
                    int k = kbase + kc * 4 + kk;
                    float4 xv0 = *(const float4*)&xh[k][m0 + 0];
                    float4 xv1 = *(const float4*)&xh[k][m0 + 4];
                    float4 xv2 = *(const float4*)&xh[k][m0 + 8];
                    float4 xv3 = *(const float4*)&xh[k][m0 + 12];
                    float wa = (kk == 0) ? wA.x : (kk == 1) ? wA.y : (kk == 2) ? wA.z : wA.w;
                    float wb = (kk == 0) ? wB.x : (kk == 1) ? wB.y : (kk == 2) ? wB.z : wB.w;
                    #pragma unroll
                    for (int q = 0; q < 4; ++q) {
                        float4 xv = (q == 0) ? xv0 : (q == 1) ? xv1 : (q == 2) ? xv2 : xv3;
                        a0[q*4+0] += wa * xv.x; a0[q*4+1] += wa * xv.y;
                        a0[q*4+2] += wa * xv.z; a0[q*4+3] += wa * xv.w;
                        a1[q*4+0] += wb * xv.x; a1[q*4+1] += wb * xv.y;
                        a1[q*4+2] += wb * xv.z; a1[q*4+3] += wb * xv.w;
                    }
                }
            }
        }
        float bf = bih[t * GATE_ROWS +  64 + j0] + bhh[t * GATE_ROWS +  64 + j0];
        float bo = bih[t * GATE_ROWS + 192 + j0] + bhh[t * GATE_ROWS + 192 + j0];
        #pragma unroll
        for (int i = 0; i < 16; ++i) {
            int m = m0 + i;
            if (m >= mcount) break;
            int e = s_perm[m];
            float fg = sigmoidf_(a0[i] + bf);
            float og = sigmoidf_(a1[i] + bo);
            float cv = c0[(size_t)e * 64 + j0];
            float ct = fg * cv + pg[i];
            float ht = og * tanhf_(ct);
            size_t o = (size_t)e * 64 + j0;
            outy[o] = ht;
            outh[o] = ht;
            outc[o] = ct;
        }
    }
}

// ---------------- launch ----------------
extern "C" void kernel_launch(void* const* d_in, const int* in_sizes, int n_in,
                              void* d_out, int out_size, void* d_ws, size_t ws_size,
                              hipStream_t stream) {
    const float* x   = (const float*)d_in[0];
    const float* h0  = (const float*)d_in[1];
    const float* c0  = (const float*)d_in[2];
    const int*   at  = (const int*)d_in[3];
    const float* Wih = (const float*)d_in[4];
    const float* Whh = (const float*)d_in[5];
    const float* bih = (const float*)d_in[6];
    const float* bhh = (const float*)d_in[7];

    float* outy = (float*)d_out;
    float* outh = outy + (size_t)B_N * 64;
    float* outc = outh + (size_t)B_N * 64;

    int* ws_i = (int*)d_ws;
    int* perm = ws_i + 64;
    unsigned short* whi = (unsigned short*)(ws_i + 64 + B_N);
    unsigned short* wlo = whi + NT * 256 * 128;

    // bytes needed for Path A: (64+B_N)*4 + 2*NT*256*128*2 = 2,097,408
    const size_t NEED_A = (size_t)(64 + B_N) * 4 + (size_t)2 * NT * 256 * 128 * 2;

    hipMemsetAsync(ws_i, 0, 32 * sizeof(int), stream);
    k_hist<<<B_N / 256, 256, 0, stream>>>(at, ws_i);
    k_scatter<<<B_N / 256, 256, 0, stream>>>(at, ws_i, perm, outy, outh, outc);

    if (ws_size >= NEED_A) {
        k_wprep<<<NT * 256 * 128 / 256, 256, 0, stream>>>(Wih, Whh, whi, wlo);
        k_mfma<<<B_N / TILE_M + NT, 256, 0, stream>>>(x, h0, c0, whi, wlo, bih, bhh,
                                                      ws_i, perm, outy, outh, outc);
    } else {
        k_gemm<<<B_N / TILE_M + NT, 256, 0, stream>>>(x, h0, c0, Wih, Whh, bih, bhh,
                                                      ws_i, perm, outy, outh, outc);
    }
}